// Round 6
// baseline (118.028 us; speedup 1.0000x reference)
//
#include <hip/hip_runtime.h>

// Simplex projection along last dim (n = 12288), rows = 4096, fp32.
// wp = max(x - tau, 0), wc = x - wp, tau solves sum(max(x-tau,0)) = Z.
//
// ONE WAVE PER ROW, ZERO BARRIERS. Each 64-lane wave holds its whole row in
// registers (48 f32x4/lane), computes bootstrap threshold stats during the
// load, solves Michelot's fixed point via ballot/shuffle (wave-level only),
// and stores wp/wc from registers. No __syncthreads -> no vmcnt(0) drains,
// no cross-block phase-locking; solve tails hide under neighbor waves' loads.
//
// Michelot: tau_{k+1} = (sum_{x>tau_k} x - Z)/|{x>tau_k}|, valid from any
// threshold t <= tau*  (g(t) = S_t - t*C_t >= Z  <=>  t <= tau*). For N(0,1)
// rows t=3 holds with ~17 actives -> compact to per-wave LDS, solve in-wave.

constexpr int   N_COLS = 12288;
constexpr int   WAVE   = 64;
constexpr int   V4     = N_COLS / (WAVE * 4);   // 48 f32x4 per lane
constexpr float Z_LVL  = 1.0f;
constexpr int   CAP    = 1024;                  // LDS compaction capacity
constexpr float T2     = 2.0f;
constexpr float T3     = 3.0f;

typedef float f32x4 __attribute__((ext_vector_type(4)));

__device__ __forceinline__ float wsum(float v) {
#pragma unroll
  for (int off = 32; off >= 1; off >>= 1) v += __shfl_xor(v, off, 64);
  return v;
}
__device__ __forceinline__ int wsumi(int v) {
#pragma unroll
  for (int off = 32; off >= 1; off >>= 1) v += __shfl_xor(v, off, 64);
  return v;
}

__global__ __launch_bounds__(WAVE, 2) void simplex_wave(
    const float* __restrict__ x, float* __restrict__ wp, float* __restrict__ wc) {

  const int    lane = threadIdx.x;
  const size_t base = (size_t)blockIdx.x * N_COLS;
  const f32x4* __restrict__ xin = reinterpret_cast<const f32x4*>(x + base);

  __shared__ float s_act[CAP];   // per-workgroup (= per-wave) scratch

  // ---- load row into registers; threshold stats accumulated under the loads ----
  f32x4 v[V4];
  float sAll = 0.f, s2 = 0.f, s3 = 0.f;
  int   c2 = 0, c3 = 0;
#pragma unroll
  for (int k = 0; k < V4; ++k) {
    v[k] = __builtin_nontemporal_load(&xin[lane + k * WAVE]);
#pragma unroll
    for (int j = 0; j < 4; ++j) {
      float e = v[k][j];
      sAll += e;
      bool a2 = e > T2, a3 = e > T3;
      s2 += a2 ? e : 0.f;  c2 += a2 ? 1 : 0;
      s3 += a3 ? e : 0.f;  c3 += a3 ? 1 : 0;
    }
  }
  const int c2l = c2, c3l = c3;       // per-lane counts (for compaction offsets)
  sAll = wsum(sAll);  s2 = wsum(s2);  s3 = wsum(s3);
  c2 = wsumi(c2);     c3 = wsumi(c3);

  // ---- pick largest valid bootstrap threshold (wave-uniform) ----
  float tf = 0.f, S0 = 0.f;
  int   C0 = 0, have = 0;
  if (c3 > 0 && c3 <= CAP && (s3 - 3.f * (float)c3) >= Z_LVL + 0.01f) {
    tf = T3; S0 = s3; C0 = c3; have = 1;
  } else if (c2 > 0 && c2 <= CAP && (s2 - 2.f * (float)c2) >= Z_LVL + 0.01f) {
    tf = T2; S0 = s2; C0 = c2; have = 1;
  }

  float tau;
  int   prev;

  if (have) {
    tau  = (S0 - Z_LVL) / (float)C0;
    prev = C0;

    // ---- compact actives {v > tf} into this wave's LDS segment ----
    const int nl = (tf == T3) ? c3l : c2l;
    int pre = nl;
#pragma unroll
    for (int off = 1; off < 64; off <<= 1) {
      int u = __shfl_up(pre, off, 64);
      if (lane >= off) pre += u;
    }
    int o = pre - nl;   // exclusive prefix
#pragma unroll
    for (int k = 0; k < V4; ++k)
#pragma unroll
      for (int j = 0; j < 4; ++j)
        if (v[k][j] > tf) s_act[o++] = v[k][j];
    asm volatile("s_waitcnt lgkmcnt(0)" ::: "memory");  // same-wave LDS RAW fence

    const int nact = C0;
    if (nact <= WAVE) {
      const bool  valid = lane < nact;
      const float a     = valid ? s_act[lane] : 0.f;
      for (int it = 0; it < 64; ++it) {
        bool  g = valid && (a > tau);
        int   C = (int)__popcll(__ballot(g));
        float s = wsum(g ? a : 0.f);
        tau = (s - Z_LVL) / (float)C;
        if (C == prev) break;
        prev = C;
      }
    } else {
      for (int it = 0; it < 64; ++it) {
        float ps = 0.f; int pc = 0;
        for (int i = lane; i < nact; i += WAVE) {
          float a = s_act[i];
          bool  g = a > tau;
          ps += g ? a : 0.f;  pc += g ? 1 : 0;
        }
        ps = wsum(ps);  pc = wsumi(pc);
        tau = (ps - Z_LVL) / (float)pc;
        if (pc == prev) break;
        prev = pc;
      }
    }
  } else {
    // ---- fallback: full-register Michelot from full-set start (any data) ----
    tau  = (sAll - Z_LVL) / (float)N_COLS;
    prev = N_COLS;
    for (int it = 0; it < 64; ++it) {
      float ps = 0.f; int pc = 0;
#pragma unroll
      for (int k = 0; k < V4; ++k)
#pragma unroll
        for (int j = 0; j < 4; ++j) {
          bool g = v[k][j] > tau;
          ps += g ? v[k][j] : 0.f;  pc += g ? 1 : 0;
        }
      ps = wsum(ps);  pc = wsumi(pc);
      tau = (ps - Z_LVL) / (float)pc;
      if (pc == prev) break;
      prev = pc;
    }
  }

  // ---- store wp / wc straight from registers (nt, coalesced 16B/lane) ----
  f32x4* __restrict__ wpo = reinterpret_cast<f32x4*>(wp + base);
  f32x4* __restrict__ wco = reinterpret_cast<f32x4*>(wc + base);
#pragma unroll
  for (int k = 0; k < V4; ++k) {
    f32x4 a = v[k], pv, cv;
#pragma unroll
    for (int j = 0; j < 4; ++j) {
      pv[j] = fmaxf(a[j] - tau, 0.f);
      cv[j] = a[j] - pv[j];
    }
    __builtin_nontemporal_store(pv, &wpo[lane + k * WAVE]);
    __builtin_nontemporal_store(cv, &wco[lane + k * WAVE]);
  }
}

extern "C" void kernel_launch(void* const* d_in, const int* in_sizes, int n_in,
                              void* d_out, int out_size, void* d_ws, size_t ws_size,
                              hipStream_t stream) {
  const float* x = (const float*)d_in[0];
  const int rows = in_sizes[0] / N_COLS;

  float* wp = (float*)d_out;
  float* wc = wp + (size_t)rows * N_COLS;

  simplex_wave<<<rows, WAVE, 0, stream>>>(x, wp, wc);
}